// Round 14
// baseline (191.161 us; speedup 1.0000x reference)
//
#include <hip/hip_runtime.h>
#include <hip/hip_fp16.h>

#define IN_DIM 16
#define HID 128
#define OUT_DIM 15

#define BKT_SIZE 256          // nodes per bucket
#define BKT_CAP  4608         // records per bucket: lambda=4096, +8 sigma
#define CNT_STRIDE 16         // ints: 64B pad per bucket counter
#define EPB 4096              // edges per bucket-sort block
#define EPT 16                // edges per thread

typedef _Float16 half8 __attribute__((ext_vector_type(8)));
typedef _Float16 h2v __attribute__((ext_vector_type(2)));
typedef float f32x4 __attribute__((ext_vector_type(4)));

union H8 { float4 f4; h2v h[4]; };
union H4 { float2 f2; h2v h[2]; };
union H4O { float2 f2; __half2 h2[2]; };

// fp16-pair accumulate into fp32 via v_dot2_f32_f16 (fp32 accumulation, exact products)
#define OX h2v{(_Float16)1.f, (_Float16)0.f}
#define OY h2v{(_Float16)0.f, (_Float16)1.f}

__device__ inline void acc8(float* a, float4 v) {
    H8 u; u.f4 = v;
#pragma unroll
    for (int k = 0; k < 4; k++) {
        a[2 * k]     = __builtin_amdgcn_fdot2(u.h[k], OX, a[2 * k], false);
        a[2 * k + 1] = __builtin_amdgcn_fdot2(u.h[k], OY, a[2 * k + 1], false);
    }
}

__device__ inline void acc4(float* a, float2 v) {
    H4 u; u.f2 = v;
#pragma unroll
    for (int k = 0; k < 2; k++) {
        a[2 * k]     = __builtin_amdgcn_fdot2(u.h[k], OX, a[2 * k], false);
        a[2 * k + 1] = __builtin_amdgcn_fdot2(u.h[k], OY, a[2 * k + 1], false);
    }
}

// ================= setup: W2/W3 MFMA fragments + zero init (one launch) =====
// blocks 0-7: W2 frags; block 8: W3 frags (col 15 zero-padded); block 9: zeros

__global__ __launch_bounds__(256) void k_setup(const float* __restrict__ W2,
                                               _Float16* __restrict__ wf,
                                               const float* __restrict__ W3,
                                               _Float16* __restrict__ wf3,
                                               int* __restrict__ bcnt, int nbkt,
                                               __half* __restrict__ xp_zr,
                                               __half* __restrict__ t16_zr,
                                               __half* __restrict__ s16_zr) {
    int blk = blockIdx.x, t = threadIdx.x;
    if (blk < 8) {
        int idx = blk * 256 + t;
        int f = idx >> 6, lane = idx & 63;
        int ct = f >> 2, kc = f & 3;
        int col = ct * 16 + (lane & 15);
        int kb  = kc * 32 + (lane >> 4) * 8;
        half8 v;
#pragma unroll
        for (int j = 0; j < 8; j++) v[j] = (_Float16)W2[(kb + j) * HID + col];
        ((half8*)wf)[idx] = v;
    } else if (blk == 8) {
        int f = t >> 6, lane = t & 63;          // f = kc 0..3
        int col = lane & 15;
        int kb  = f * 32 + (lane >> 4) * 8;
        half8 v;
#pragma unroll
        for (int j = 0; j < 8; j++)
            v[j] = (col < OUT_DIM) ? (_Float16)W3[(kb + j) * OUT_DIM + col]
                                   : (_Float16)0.f;
        ((half8*)wf3)[f * 64 + lane] = v;
    } else {
        for (int i = t; i < nbkt * CNT_STRIDE; i += 256) bcnt[i] = 0;
        __half z = __float2half(0.f);
        if (t < 16)  xp_zr[t]  = z;
        if (t < 128) t16_zr[t] = z;
        if (t < 16)  s16_zr[t] = z;
    }
}

// ================= adjacency build: block-local counting sort =================

__global__ __launch_bounds__(256) void k_bucket(const int* __restrict__ src,
                                                const int* __restrict__ dst,
                                                int* __restrict__ bcnt,
                                                int* __restrict__ ebuf,
                                                int e, int nbkt) {
    __shared__ int hist[512];
    __shared__ int cur[512];
    __shared__ int adj[512];
    __shared__ int wsum[4];
    int t = threadIdx.x;
    int base_i = blockIdx.x * EPB;
    int rec[EPT], bk[EPT];
#pragma unroll
    for (int j = 0; j < EPT; j++) {
        int i = base_i + j * 256 + t;
        if (i < e) {
            int d = dst[i];
            bk[j] = d >> 8;
            rec[j] = (int)((((unsigned)d & 255u) << 24) | (unsigned)src[i]);
        } else bk[j] = -1;
    }
    hist[t] = 0; hist[t + 256] = 0;
    __syncthreads();
#pragma unroll
    for (int j = 0; j < EPT; j++)
        if (bk[j] >= 0) atomicAdd(&hist[bk[j]], 1);
    __syncthreads();
    // scan over 512 buckets: thread t owns entries 2t, 2t+1; shfl wave-scan
    int h0 = hist[2 * t], h1 = hist[2 * t + 1];
    int loc = h0 + h1;
    int inc = loc;
#pragma unroll
    for (int o = 1; o < 64; o <<= 1) {
        int u = __shfl_up(inc, o, 64);
        if ((t & 63) >= o) inc += u;
    }
    if ((t & 63) == 63) wsum[t >> 6] = inc;
    __syncthreads();
    int woff = 0;
#pragma unroll
    for (int w = 0; w < 4; w++) if (w < (t >> 6)) woff += wsum[w];
    int exc0 = woff + inc - loc;
    int exc1 = exc0 + h0;
    cur[2 * t] = exc0; cur[2 * t + 1] = exc1;
    if (h0 > 0 && 2 * t < nbkt)
        adj[2 * t] = atomicAdd(&bcnt[(2 * t) * CNT_STRIDE], h0) - exc0;
    if (h1 > 0 && 2 * t + 1 < nbkt)
        adj[2 * t + 1] = atomicAdd(&bcnt[(2 * t + 1) * CNT_STRIDE], h1) - exc1;
    __syncthreads();
#pragma unroll
    for (int j = 0; j < EPT; j++) {
        int b = bk[j];
        if (b < 0) continue;
        int p = atomicAdd(&cur[b], 1);
        int pos = adj[b] + p;
        if (pos < BKT_CAP)
            ebuf[(size_t)b * BKT_CAP + pos] = rec[j];
    }
}

// Pass B: one block per bucket; records in REGISTERS; fused prescale
// (xp = fp16(x*dis)) for the bucket's 256 nodes using LDS-resident hist.
// Validity is index<cnt -- NEVER the record value (bit 31 can be set).

__global__ __launch_bounds__(256) void k_build(const int* __restrict__ bcnt,
                                               int* __restrict__ ebuf,
                                               int* __restrict__ deg,
                                               int* __restrict__ offs,
                                               const float* __restrict__ x,
                                               __half* __restrict__ xp, int n) {
    __shared__ int hist[256];
    __shared__ int cur[256];
    __shared__ int wsum[4];
    int b = blockIdx.x, t = threadIdx.x;
    int cnt = bcnt[b * CNT_STRIDE];
    if (cnt > BKT_CAP) cnt = BKT_CAP;
    size_t gbase = (size_t)b * BKT_CAP;
    int r[18];
#pragma unroll
    for (int k = 0; k < 18; k++) {
        int i = t + k * 256;
        r[k] = (i < cnt) ? ebuf[gbase + i] : 0;
    }
    hist[t] = 0;
    __syncthreads();
#pragma unroll
    for (int k = 0; k < 18; k++) {
        int i = t + k * 256;
        if (i < cnt) atomicAdd(&hist[((unsigned)r[k]) >> 24], 1);
    }
    __syncthreads();
    int h = hist[t];
    int inc = h;
#pragma unroll
    for (int o = 1; o < 64; o <<= 1) {
        int u = __shfl_up(inc, o, 64);
        if ((t & 63) >= o) inc += u;
    }
    if ((t & 63) == 63) wsum[t >> 6] = inc;
    __syncthreads();
    int woff = 0;
#pragma unroll
    for (int w = 0; w < 4; w++) if (w < (t >> 6)) woff += wsum[w];
    int exc = woff + inc - h;
    int node = b * BKT_SIZE + t;
    if (node < n) {
        deg[node]  = h;
        offs[node] = (int)gbase + exc;
    }
    cur[t] = exc;
    __syncthreads();
#pragma unroll
    for (int k = 0; k < 18; k++) {
        int i = t + k * 256;
        if (i < cnt) {
            int l = ((unsigned)r[k]) >> 24;
            int p = atomicAdd(&cur[l], 1);
            ebuf[gbase + p] = r[k] & 0xFFFFFF;
        }
    }
    // ---- fused prescale: xp = fp16(x * rsqrt(1+deg)) for this bucket ----
    int base_n = b * BKT_SIZE;
    const float4* x4 = (const float4*)x;
#pragma unroll
    for (int i = t; i < 1024; i += 256) {    // 256 nodes x 4 float4
        int ln = i >> 2, quad = i & 3;
        int nn = base_n + ln;
        if (nn < n) {
            float dv = rsqrtf(1.0f + (float)hist[ln]);
            float4 v = x4[(size_t)nn * 4 + quad];
            H4O u;
            u.h2[0] = __floats2half2_rn(v.x * dv, v.y * dv);
            u.h2[1] = __floats2half2_rn(v.z * dv, v.w * dv);
            ((float2*)xp)[(size_t)nn * 4 + quad] = u.f2;
        }
    }
}

// ================= fused 16-dim aggregate + GEMM1, 4 nodes per wave =========
// lane = q*16 + g*4 + c: quarter q owns node wid*4+q; 4 groups gather;
// reduce = 2 shfl rounds; broadcast within quarter; GEMM1 = 8 cols/lane.

__global__ __launch_bounds__(256) void k_agg16g(const int* __restrict__ deg,
                                                const int* __restrict__ offs,
                                                const int* __restrict__ csr,
                                                const __half* __restrict__ xp,
                                                const float* __restrict__ W1,
                                                const float* __restrict__ b1,
                                                _Float16* __restrict__ h1, int n) {
    int wid = (blockIdx.x * blockDim.x + threadIdx.x) >> 6;
    int lane = threadIdx.x & 63;
    int q = lane >> 4, g = (lane >> 2) & 3, c = lane & 3;
    int node = wid * 4 + q;
    bool valid = node < n;
    int nodec = valid ? node : n - 1;
    int d = deg[nodec];
    int beg = offs[nodec];
    const float2* x2 = (const float2*)xp;   // row = 4 float2
    // wave-uniform loop bound: max degree across the 4 quarters
    int dmax = d;
    dmax = max(dmax, __shfl_xor(dmax, 16, 64));
    dmax = max(dmax, __shfl_xor(dmax, 32, 64));
    float a[4]  = {0.f, 0.f, 0.f, 0.f};
    float b4[4] = {0.f, 0.f, 0.f, 0.f};
    for (int j = g; j < dmax; j += 8) {
        int j1 = j + 4;
        int s0 = (j  < d) ? csr[beg + j]  : n;   // n = zero row
        int s1 = (j1 < d) ? csr[beg + j1] : n;
        float2 v0 = x2[(size_t)s0 * 4 + c];
        float2 v1 = x2[(size_t)s1 * 4 + c];
        acc4(a, v0);
        acc4(b4, v1);
    }
#pragma unroll
    for (int k = 0; k < 4; k++) a[k] += b4[k];
    // reduce across the 4 groups (lane bits 2-3)
#pragma unroll
    for (int k = 0; k < 4; k++) a[k] += __shfl_xor(a[k], 4, 64);
#pragma unroll
    for (int k = 0; k < 4; k++) a[k] += __shfl_xor(a[k], 8, 64);
    acc4(a, x2[(size_t)nodec * 4 + c]);   // self (replicated across g)
    float dv = rsqrtf(1.0f + (float)d);
#pragma unroll
    for (int k = 0; k < 4; k++) a[k] *= dv;
    // broadcast the 16 xa values within each quarter
    float xaf[16];
    int qbase = lane & ~15;
#pragma unroll
    for (int cc = 0; cc < 4; cc++) {
#pragma unroll
        for (int k = 0; k < 4; k++)
            xaf[cc * 4 + k] = __shfl(a[k], qbase + cc, 64);
    }
    // GEMM1: lane p = lane&15 computes cols p*8 .. p*8+7 of its quarter's node
    int p = lane & 15;
    const float4* W14 = (const float4*)W1;   // row k = 32 float4
    float s[8] = {0.f, 0.f, 0.f, 0.f, 0.f, 0.f, 0.f, 0.f};
#pragma unroll
    for (int k = 0; k < 16; k++) {
        float xv = xaf[k];
        float4 w0 = W14[k * 32 + p * 2];
        float4 w1 = W14[k * 32 + p * 2 + 1];
        s[0] = fmaf(xv, w0.x, s[0]); s[1] = fmaf(xv, w0.y, s[1]);
        s[2] = fmaf(xv, w0.z, s[2]); s[3] = fmaf(xv, w0.w, s[3]);
        s[4] = fmaf(xv, w1.x, s[4]); s[5] = fmaf(xv, w1.y, s[5]);
        s[6] = fmaf(xv, w1.z, s[6]); s[7] = fmaf(xv, w1.w, s[7]);
    }
    float4 bb0 = ((const float4*)b1)[p * 2];
    float4 bb1 = ((const float4*)b1)[p * 2 + 1];
    half8 o;
    o[0] = (_Float16)fmaxf(s[0] + bb0.x, 0.f);
    o[1] = (_Float16)fmaxf(s[1] + bb0.y, 0.f);
    o[2] = (_Float16)fmaxf(s[2] + bb0.z, 0.f);
    o[3] = (_Float16)fmaxf(s[3] + bb0.w, 0.f);
    o[4] = (_Float16)fmaxf(s[4] + bb1.x, 0.f);
    o[5] = (_Float16)fmaxf(s[5] + bb1.y, 0.f);
    o[6] = (_Float16)fmaxf(s[6] + bb1.z, 0.f);
    o[7] = (_Float16)fmaxf(s[7] + bb1.w, 0.f);
    if (valid) ((half8*)h1)[(size_t)node * 16 + p] = o;
}

// ================= GEMM2 on matrix cores =================

__global__ __launch_bounds__(256) void k_gemm2m(const _Float16* __restrict__ h1,
                                                const half8* __restrict__ wf,
                                                const int* __restrict__ deg,
                                                __half* __restrict__ t16,
                                                int n, int ntiles) {
    int t = threadIdx.x;
    int wave = t >> 6, lane = t & 63;
    int chalf = wave & 1;                 // col half: 0 -> cols 0-63, 1 -> 64-127
    half8 B0[4], B1[4], B2[4], B3[4];     // [ct 0..3][kc 0..3] for this half
#pragma unroll
    for (int kc = 0; kc < 4; kc++) {
        B0[kc] = wf[(((chalf * 4 + 0) * 4 + kc)) * 64 + lane];
        B1[kc] = wf[(((chalf * 4 + 1) * 4 + kc)) * 64 + lane];
        B2[kc] = wf[(((chalf * 4 + 2) * 4 + kc)) * 64 + lane];
        B3[kc] = wf[(((chalf * 4 + 3) * 4 + kc)) * 64 + lane];
    }
    int r = lane & 15, kg = lane >> 4;
    const half8* h8 = (const half8*)h1;
    int tile0 = blockIdx.x * 2 + (wave >> 1);
    int step  = gridDim.x * 2;
    for (int tile = tile0; tile < ntiles; tile += step) {
        int row = tile * 16 + r;
        int rowc = row < n ? row : n - 1;
        half8 a[4];
#pragma unroll
        for (int kc = 0; kc < 4; kc++) a[kc] = h8[(size_t)rowc * 16 + kc * 4 + kg];
        f32x4 z = {0.f, 0.f, 0.f, 0.f};
        f32x4 acc0 = z, acc1 = z, acc2 = z, acc3 = z;
#pragma unroll
        for (int kc = 0; kc < 4; kc++) {
            acc0 = __builtin_amdgcn_mfma_f32_16x16x32_f16(a[kc], B0[kc], acc0, 0, 0, 0);
            acc1 = __builtin_amdgcn_mfma_f32_16x16x32_f16(a[kc], B1[kc], acc1, 0, 0, 0);
            acc2 = __builtin_amdgcn_mfma_f32_16x16x32_f16(a[kc], B2[kc], acc2, 0, 0, 0);
            acc3 = __builtin_amdgcn_mfma_f32_16x16x32_f16(a[kc], B3[kc], acc3, 0, 0, 0);
        }
        int colb = chalf * 64 + r;
#pragma unroll
        for (int j = 0; j < 4; j++) {
            int orow = tile * 16 + kg * 4 + j;
            if (orow < n) {
                float dv = rsqrtf(1.0f + (float)deg[orow]);
                size_t base = (size_t)orow * HID + colb;
                t16[base]      = __float2half(acc0[j] * dv);
                t16[base + 16] = __float2half(acc1[j] * dv);
                t16[base + 32] = __float2half(acc2[j] * dv);
                t16[base + 48] = __float2half(acc3[j] * dv);
            }
        }
    }
}

// ================= 128-dim aggregate (fp16 in/out) =================
// Main loop: full 16-edge windows, NO bounds checks (j+16 <= d).
// Tail: 4-edge windows (8 fdot2/iter instead of 32).

__global__ __launch_bounds__(256) void k_agg128(const int* __restrict__ deg,
                                                const int* __restrict__ offs,
                                                const int* __restrict__ csr,
                                                const __half* __restrict__ t16,
                                                const float* __restrict__ b,
                                                __half* __restrict__ h2o, int n) {
    int wid = (blockIdx.x * blockDim.x + threadIdx.x) >> 6;
    int lane = threadIdx.x & 63;
    if (wid >= n) return;
    int q = lane >> 4, c = lane & 15;
    int d = deg[wid];
    int beg = offs[wid];
    const float4* t4 = (const float4*)t16;  // row = 16 float4 (256B)
    float a0[8] = {0,0,0,0,0,0,0,0};
    float a1[8] = {0,0,0,0,0,0,0,0};
    int j = 0;
    for (; j + 16 <= d; j += 16) {          // unconditional window
        int s0 = csr[beg + j + q];
        int s1 = csr[beg + j + 4 + q];
        int s2 = csr[beg + j + 8 + q];
        int s3 = csr[beg + j + 12 + q];
        float4 v0 = t4[(size_t)s0 * 16 + c];
        float4 v1 = t4[(size_t)s1 * 16 + c];
        float4 v2 = t4[(size_t)s2 * 16 + c];
        float4 v3 = t4[(size_t)s3 * 16 + c];
        acc8(a0, v0);
        acc8(a1, v1);
        acc8(a0, v2);
        acc8(a1, v3);
    }
    for (; j < d; j += 4) {                 // tail: 4 edges/iter
        int jq = j + q;
        int s0 = (jq < d) ? csr[beg + jq] : n;   // n = zero row
        float4 v0 = t4[(size_t)s0 * 16 + c];
        acc8(a0, v0);
    }
#pragma unroll
    for (int k = 0; k < 8; k++) a0[k] += a1[k];
#pragma unroll
    for (int k = 0; k < 8; k++) a0[k] += __shfl_xor(a0[k], 16, 64);
#pragma unroll
    for (int k = 0; k < 8; k++) a0[k] += __shfl_xor(a0[k], 32, 64);
    if (q == 0) {
        acc8(a0, t4[(size_t)wid * 16 + c]);   // self
        float dv = rsqrtf(1.0f + (float)d);
        float4 bb0 = ((const float4*)b)[c * 2];
        float4 bb1 = ((const float4*)b)[c * 2 + 1];
        float r[8];
        r[0] = fmaxf(fmaf(a0[0], dv, bb0.x), 0.f);
        r[1] = fmaxf(fmaf(a0[1], dv, bb0.y), 0.f);
        r[2] = fmaxf(fmaf(a0[2], dv, bb0.z), 0.f);
        r[3] = fmaxf(fmaf(a0[3], dv, bb0.w), 0.f);
        r[4] = fmaxf(fmaf(a0[4], dv, bb1.x), 0.f);
        r[5] = fmaxf(fmaf(a0[5], dv, bb1.y), 0.f);
        r[6] = fmaxf(fmaf(a0[6], dv, bb1.z), 0.f);
        r[7] = fmaxf(fmaf(a0[7], dv, bb1.w), 0.f);
        H4O u0, u1;
        u0.h2[0] = __floats2half2_rn(r[0], r[1]);
        u0.h2[1] = __floats2half2_rn(r[2], r[3]);
        u1.h2[0] = __floats2half2_rn(r[4], r[5]);
        u1.h2[1] = __floats2half2_rn(r[6], r[7]);
        float4 o = {u0.f2.x, u0.f2.y, u1.f2.x, u1.f2.y};
        ((float4*)h2o)[(size_t)wid * 16 + c] = o;
    }
}

// ================= GEMM3 on matrix cores: s16 = fp16((h2 @ W3pad16)*dis) =====

__global__ __launch_bounds__(256) void k_gemm3m(const __half* __restrict__ h2,
                                                const half8* __restrict__ wf3,
                                                const int* __restrict__ deg,
                                                __half* __restrict__ s16,
                                                int n, int ntiles) {
    int t = threadIdx.x;
    int wave = t >> 6, lane = t & 63;
    int tile = blockIdx.x * 4 + wave;
    if (tile >= ntiles) return;
    half8 B[4];
#pragma unroll
    for (int kc = 0; kc < 4; kc++) B[kc] = wf3[kc * 64 + lane];
    int r = lane & 15, kg = lane >> 4;
    const half8* h8 = (const half8*)h2;
    int row = tile * 16 + r;
    int rowc = row < n ? row : n - 1;
    half8 a[4];
#pragma unroll
    for (int kc = 0; kc < 4; kc++) a[kc] = h8[(size_t)rowc * 16 + kc * 4 + kg];
    f32x4 acc = {0.f, 0.f, 0.f, 0.f};
#pragma unroll
    for (int kc = 0; kc < 4; kc++)
        acc = __builtin_amdgcn_mfma_f32_16x16x32_f16(a[kc], B[kc], acc, 0, 0, 0);
#pragma unroll
    for (int j = 0; j < 4; j++) {
        int orow = tile * 16 + kg * 4 + j;
        if (orow < n) {
            float dv = rsqrtf(1.0f + (float)deg[orow]);
            s16[(size_t)orow * 16 + r] = __float2half(acc[j] * dv);
        }
    }
}

// ================= 15-dim aggregate, 4 nodes per wave =================

__global__ __launch_bounds__(256) void k_agg15(const int* __restrict__ deg,
                                               const int* __restrict__ offs,
                                               const int* __restrict__ csr,
                                               const __half* __restrict__ s16,
                                               const float* __restrict__ b,
                                               float* __restrict__ out, int n) {
    int wid = (blockIdx.x * blockDim.x + threadIdx.x) >> 6;
    int lane = threadIdx.x & 63;
    int q = lane >> 4, g = (lane >> 2) & 3, c = lane & 3;
    int node = wid * 4 + q;
    bool valid = node < n;
    int nodec = valid ? node : n - 1;
    int d = deg[nodec];
    int beg = offs[nodec];
    const float2* s2 = (const float2*)s16;  // row = 4 float2 (16 halfs padded)
    int dmax = d;
    dmax = max(dmax, __shfl_xor(dmax, 16, 64));
    dmax = max(dmax, __shfl_xor(dmax, 32, 64));
    float a[4]  = {0.f, 0.f, 0.f, 0.f};
    float b4[4] = {0.f, 0.f, 0.f, 0.f};
    for (int j = g; j < dmax; j += 8) {
        int j1 = j + 4;
        int s0 = (j  < d) ? csr[beg + j]  : n;   // n = zero row
        int s1 = (j1 < d) ? csr[beg + j1] : n;
        float2 v0 = s2[(size_t)s0 * 4 + c];
        float2 v1 = s2[(size_t)s1 * 4 + c];
        acc4(a, v0);
        acc4(b4, v1);
    }
#pragma unroll
    for (int k = 0; k < 4; k++) a[k] += b4[k];
#pragma unroll
    for (int k = 0; k < 4; k++) a[k] += __shfl_xor(a[k], 4, 64);
#pragma unroll
    for (int k = 0; k < 4; k++) a[k] += __shfl_xor(a[k], 8, 64);
    if (valid && g == 0) {
        acc4(a, s2[(size_t)node * 4 + c]);   // self
        float dv = rsqrtf(1.0f + (float)d);
#pragma unroll
        for (int k = 0; k < 4; k++) {
            int f = c * 4 + k;
            if (f < OUT_DIM)
                out[(size_t)node * OUT_DIM + f] = fmaf(a[k], dv, b[f]);
        }
    }
}

// ================= launch =================

extern "C" void kernel_launch(void* const* d_in, const int* in_sizes, int n_in,
                              void* d_out, int out_size, void* d_ws, size_t ws_size,
                              hipStream_t stream) {
    const float* x  = (const float*)d_in[0];
    const int*   ei = (const int*)d_in[1];
    const float* W1 = (const float*)d_in[2];
    const float* b1 = (const float*)d_in[3];
    const float* W2 = (const float*)d_in[4];
    const float* b2 = (const float*)d_in[5];
    const float* W3 = (const float*)d_in[6];
    const float* b3 = (const float*)d_in[7];
    int n = in_sizes[0] / IN_DIM;
    int e = in_sizes[1] / 2;
    const int* src = ei;
    const int* dst = ei + e;
    float* out = (float*)d_out;

    int nbkt = (n + BKT_SIZE - 1) / BKT_SIZE;   // 391

    // ---- workspace layout (256B-aligned segments) ----
    char* WS = (char*)d_ws;
    size_t off = 0;
    auto alloc = [&](size_t bytes) {
        char* p = WS + off;
        off = (off + bytes + 255) & ~(size_t)255;
        return p;
    };
    int*      deg  = (int*)     alloc((size_t)n * 4);
    int*      offs = (int*)     alloc((size_t)n * 4);
    int*      bcnt = (int*)     alloc((size_t)nbkt * CNT_STRIDE * 4);
    int*      ebuf = (int*)     alloc(((size_t)nbkt * BKT_CAP + 64) * 4);  // +pad for clamped over-reads
    __half*   xp   = (__half*)  alloc((size_t)(n + 1) * IN_DIM * 2);      // +1 zero row
    _Float16* h1   = (_Float16*)alloc((size_t)n * HID * 2);
    _Float16* wf   = (_Float16*)alloc((size_t)2048 * 8 * 2);
    _Float16* wf3  = (_Float16*)alloc((size_t)256 * 8 * 2);
    __half*   t16  = (__half*)  alloc((size_t)(n + 1) * HID * 2);         // +1 zero row
    __half*   h2   = (__half*)  alloc((size_t)n * HID * 2);
    __half*   s16  = (__half*)  alloc((size_t)(n + 1) * 16 * 2);          // +1 zero row

    const int B = 256;
    int ntiles = (n + 15) / 16;   // 6250

    // ---- setup: W2/W3 frags + bcnt zero + zero rows (one launch) ----
    k_setup<<<10, B, 0, stream>>>(W2, wf, W3, wf3, bcnt, nbkt,
                                  xp + (size_t)n * IN_DIM,
                                  t16 + (size_t)n * HID,
                                  s16 + (size_t)n * 16);

    // ---- adjacency build (build also emits xp = fp16(dis*x)) ----
    k_bucket<<<(e + EPB - 1) / EPB, B, 0, stream>>>(src, dst, bcnt, ebuf, e, nbkt);
    k_build <<<nbkt, B, 0, stream>>>(bcnt, ebuf, deg, offs, x, xp, n);

    // ---- layer 1: fused agg16+GEMM1 (4 nodes/wave) -> h1 ----
    k_agg16g<<<((size_t)n * 16 + B - 1) / B, B, 0, stream>>>(deg, offs, ebuf, xp, W1, b1, h1, n);

    // ---- GEMM2 (MFMA) -> t16 ----
    k_gemm2m<<<(ntiles + 1) / 2, B, 0, stream>>>(h1, (const half8*)wf, deg, t16, n, ntiles);

    // ---- layer 2 aggregate -> h2 (fp16) ----
    k_agg128<<<((size_t)n * 64 + B - 1) / B, B, 0, stream>>>(deg, offs, ebuf, t16, b2, h2, n);

    // ---- layer 3: GEMM3 (MFMA) -> s16 ; agg15 (4 nodes/wave) -> out ----
    k_gemm3m<<<(ntiles + 3) / 4, B, 0, stream>>>(h2, (const half8*)wf3, deg, s16, n, ntiles);
    k_agg15 <<<((size_t)n * 16 + B - 1) / B, B, 0, stream>>>(deg, offs, ebuf, s16, b3, out, n);
}

// Round 15
// 161.804 us; speedup vs baseline: 1.1814x; 1.1814x over previous
//
#include <hip/hip_runtime.h>
#include <hip/hip_fp16.h>

#define IN_DIM 16
#define HID 128
#define OUT_DIM 15

#define BKT_SIZE 256          // nodes per bucket
#define BKT_CAP  4608         // records per bucket: lambda=4096, +8 sigma
#define CNT_STRIDE 16         // ints: 64B pad per bucket counter
#define EPB 4096              // edges per bucket-sort block
#define EPT 16                // edges per thread

typedef _Float16 half8 __attribute__((ext_vector_type(8)));
typedef _Float16 half4v __attribute__((ext_vector_type(4)));
typedef _Float16 h2v __attribute__((ext_vector_type(2)));
typedef float f32x4 __attribute__((ext_vector_type(4)));

union H8 { float4 f4; h2v h[4]; };
union H4 { float2 f2; h2v h[2]; };
union H4O { float2 f2; __half2 h2[2]; };

// fp16-pair accumulate into fp32 via v_dot2_f32_f16 (fp32 accumulation, exact products)
#define OX h2v{(_Float16)1.f, (_Float16)0.f}
#define OY h2v{(_Float16)0.f, (_Float16)1.f}

__device__ inline void acc8(float* a, float4 v) {
    H8 u; u.f4 = v;
#pragma unroll
    for (int k = 0; k < 4; k++) {
        a[2 * k]     = __builtin_amdgcn_fdot2(u.h[k], OX, a[2 * k], false);
        a[2 * k + 1] = __builtin_amdgcn_fdot2(u.h[k], OY, a[2 * k + 1], false);
    }
}

__device__ inline void acc4(float* a, float2 v) {
    H4 u; u.f2 = v;
#pragma unroll
    for (int k = 0; k < 2; k++) {
        a[2 * k]     = __builtin_amdgcn_fdot2(u.h[k], OX, a[2 * k], false);
        a[2 * k + 1] = __builtin_amdgcn_fdot2(u.h[k], OY, a[2 * k + 1], false);
    }
}

// ================= setup: W1/W2/W3 MFMA fragments + zero init (one launch) ==
// blocks 0-7: W2 frags; 8: W3 frags (col15 zero); 9: bcnt zero + zero rows;
// 10: W1 frags (K padded 16->32 with zeros).

__global__ __launch_bounds__(256) void k_setup(const float* __restrict__ W2,
                                               _Float16* __restrict__ wf,
                                               const float* __restrict__ W3,
                                               _Float16* __restrict__ wf3,
                                               const float* __restrict__ W1,
                                               _Float16* __restrict__ w1f,
                                               int* __restrict__ bcnt, int nbkt,
                                               __half* __restrict__ xp_zr,
                                               __half* __restrict__ t16_zr,
                                               __half* __restrict__ s16_zr) {
    int blk = blockIdx.x, t = threadIdx.x;
    if (blk < 8) {
        int idx = blk * 256 + t;
        int f = idx >> 6, lane = idx & 63;
        int ct = f >> 2, kc = f & 3;
        int col = ct * 16 + (lane & 15);
        int kb  = kc * 32 + (lane >> 4) * 8;
        half8 v;
#pragma unroll
        for (int j = 0; j < 8; j++) v[j] = (_Float16)W2[(kb + j) * HID + col];
        ((half8*)wf)[idx] = v;
    } else if (blk == 8) {
        int f = t >> 6, lane = t & 63;          // f = kc 0..3
        int col = lane & 15;
        int kb  = f * 32 + (lane >> 4) * 8;
        half8 v;
#pragma unroll
        for (int j = 0; j < 8; j++)
            v[j] = (col < OUT_DIM) ? (_Float16)W3[(kb + j) * OUT_DIM + col]
                                   : (_Float16)0.f;
        ((half8*)wf3)[f * 64 + lane] = v;
    } else if (blk == 9) {
        for (int i = t; i < nbkt * CNT_STRIDE; i += 256) bcnt[i] = 0;
        __half z = __float2half(0.f);
        if (t < 16)  xp_zr[t]  = z;
        if (t < 128) t16_zr[t] = z;
        if (t < 16)  s16_zr[t] = z;
    } else {
        // W1 (16x128) -> 8 col-tile B-frags for mfma_16x16x32, k>=16 zeroed
#pragma unroll
        for (int i = t; i < 512; i += 256) {
            int f = i >> 6, lane = i & 63;      // f = ct 0..7
            int col = f * 16 + (lane & 15);
            int kg  = lane >> 4;
            half8 v;
#pragma unroll
            for (int j = 0; j < 8; j++) {
                int k = kg * 8 + j;
                v[j] = (k < 16) ? (_Float16)W1[k * HID + col] : (_Float16)0.f;
            }
            ((half8*)w1f)[i] = v;
        }
    }
}

// ================= adjacency build: block-local counting sort =================

__global__ __launch_bounds__(256) void k_bucket(const int* __restrict__ src,
                                                const int* __restrict__ dst,
                                                int* __restrict__ bcnt,
                                                int* __restrict__ ebuf,
                                                int e, int nbkt) {
    __shared__ int hist[512];
    __shared__ int cur[512];
    __shared__ int adj[512];
    __shared__ int wsum[4];
    int t = threadIdx.x;
    int base_i = blockIdx.x * EPB;
    int rec[EPT], bk[EPT];
#pragma unroll
    for (int j = 0; j < EPT; j++) {
        int i = base_i + j * 256 + t;
        if (i < e) {
            int d = dst[i];
            bk[j] = d >> 8;
            rec[j] = (int)((((unsigned)d & 255u) << 24) | (unsigned)src[i]);
        } else bk[j] = -1;
    }
    hist[t] = 0; hist[t + 256] = 0;
    __syncthreads();
#pragma unroll
    for (int j = 0; j < EPT; j++)
        if (bk[j] >= 0) atomicAdd(&hist[bk[j]], 1);
    __syncthreads();
    int h0 = hist[2 * t], h1 = hist[2 * t + 1];
    int loc = h0 + h1;
    int inc = loc;
#pragma unroll
    for (int o = 1; o < 64; o <<= 1) {
        int u = __shfl_up(inc, o, 64);
        if ((t & 63) >= o) inc += u;
    }
    if ((t & 63) == 63) wsum[t >> 6] = inc;
    __syncthreads();
    int woff = 0;
#pragma unroll
    for (int w = 0; w < 4; w++) if (w < (t >> 6)) woff += wsum[w];
    int exc0 = woff + inc - loc;
    int exc1 = exc0 + h0;
    cur[2 * t] = exc0; cur[2 * t + 1] = exc1;
    if (h0 > 0 && 2 * t < nbkt)
        adj[2 * t] = atomicAdd(&bcnt[(2 * t) * CNT_STRIDE], h0) - exc0;
    if (h1 > 0 && 2 * t + 1 < nbkt)
        adj[2 * t + 1] = atomicAdd(&bcnt[(2 * t + 1) * CNT_STRIDE], h1) - exc1;
    __syncthreads();
#pragma unroll
    for (int j = 0; j < EPT; j++) {
        int b = bk[j];
        if (b < 0) continue;
        int p = atomicAdd(&cur[b], 1);
        int pos = adj[b] + p;
        if (pos < BKT_CAP)
            ebuf[(size_t)b * BKT_CAP + pos] = rec[j];
    }
}

// Pass B: one block per bucket; records in REGISTERS; fused prescale.
// Validity is index<cnt -- NEVER the record value (bit 31 can be set).

__global__ __launch_bounds__(256) void k_build(const int* __restrict__ bcnt,
                                               int* __restrict__ ebuf,
                                               int* __restrict__ deg,
                                               int* __restrict__ offs,
                                               const float* __restrict__ x,
                                               __half* __restrict__ xp, int n) {
    __shared__ int hist[256];
    __shared__ int cur[256];
    __shared__ int wsum[4];
    int b = blockIdx.x, t = threadIdx.x;
    int cnt = bcnt[b * CNT_STRIDE];
    if (cnt > BKT_CAP) cnt = BKT_CAP;
    size_t gbase = (size_t)b * BKT_CAP;
    int r[18];
#pragma unroll
    for (int k = 0; k < 18; k++) {
        int i = t + k * 256;
        r[k] = (i < cnt) ? ebuf[gbase + i] : 0;
    }
    hist[t] = 0;
    __syncthreads();
#pragma unroll
    for (int k = 0; k < 18; k++) {
        int i = t + k * 256;
        if (i < cnt) atomicAdd(&hist[((unsigned)r[k]) >> 24], 1);
    }
    __syncthreads();
    int h = hist[t];
    int inc = h;
#pragma unroll
    for (int o = 1; o < 64; o <<= 1) {
        int u = __shfl_up(inc, o, 64);
        if ((t & 63) >= o) inc += u;
    }
    if ((t & 63) == 63) wsum[t >> 6] = inc;
    __syncthreads();
    int woff = 0;
#pragma unroll
    for (int w = 0; w < 4; w++) if (w < (t >> 6)) woff += wsum[w];
    int exc = woff + inc - h;
    int node = b * BKT_SIZE + t;
    if (node < n) {
        deg[node]  = h;
        offs[node] = (int)gbase + exc;
    }
    cur[t] = exc;
    __syncthreads();
#pragma unroll
    for (int k = 0; k < 18; k++) {
        int i = t + k * 256;
        if (i < cnt) {
            int l = ((unsigned)r[k]) >> 24;
            int p = atomicAdd(&cur[l], 1);
            ebuf[gbase + p] = r[k] & 0xFFFFFF;
        }
    }
    // fused prescale: xp = fp16(x * rsqrt(1+deg)) for this bucket
    int base_n = b * BKT_SIZE;
    const float4* x4 = (const float4*)x;
#pragma unroll
    for (int i = t; i < 1024; i += 256) {    // 256 nodes x 4 float4
        int ln = i >> 2, quad = i & 3;
        int nn = base_n + ln;
        if (nn < n) {
            float dv = rsqrtf(1.0f + (float)hist[ln]);
            float4 v = x4[(size_t)nn * 4 + quad];
            H4O u;
            u.h2[0] = __floats2half2_rn(v.x * dv, v.y * dv);
            u.h2[1] = __floats2half2_rn(v.z * dv, v.w * dv);
            ((float2*)xp)[(size_t)nn * 4 + quad] = u.f2;
        }
    }
}

// ================= fused layer-1: agg16 -> MFMA GEMM1 -> MFMA GEMM2 =========
// Block = 16 nodes. Phase 1: wave w aggregates nodes w*4..w*4+3 (4 groups x
// 4 cols per node), xa -> LDS fp16. Phase 2: each wave mfma's 2 col-tiles of
// h1 = relu(xa@W1+b1) (K padded 16->32) into LDS. Phase 3: each wave mfma's
// its 32-col block of t16 = fp16((h1@W2)*dis).

__global__ __launch_bounds__(256) void k_l1fused(const int* __restrict__ deg,
                                                 const int* __restrict__ offs,
                                                 const int* __restrict__ csr,
                                                 const __half* __restrict__ xp,
                                                 const half8* __restrict__ w1f,
                                                 const float* __restrict__ b1,
                                                 const half8* __restrict__ wf,
                                                 __half* __restrict__ t16, int n) {
    __shared__ _Float16 xal[16][24];    // 16 nodes x 16 dims, pad 24 (48B rows)
    __shared__ _Float16 h1l[16][136];   // 16 x 128, pad 136 (272B rows)
    int t = threadIdx.x;
    int wave = t >> 6, lane = t & 63;
    int q = lane >> 4, g = (lane >> 2) & 3, c = lane & 3;
    int node0 = blockIdx.x * 16;
    int node = node0 + wave * 4 + q;
    bool valid = node < n;
    int nodec = valid ? node : n - 1;
    int d = deg[nodec];
    int beg = offs[nodec];
    const float2* x2 = (const float2*)xp;   // row = 4 float2
    int dmax = d;
    dmax = max(dmax, __shfl_xor(dmax, 16, 64));
    dmax = max(dmax, __shfl_xor(dmax, 32, 64));
    float a[4]  = {0.f, 0.f, 0.f, 0.f};
    float a2[4] = {0.f, 0.f, 0.f, 0.f};
    for (int j = g; j < dmax; j += 8) {
        int j1 = j + 4;
        int s0 = (j  < d) ? csr[beg + j]  : n;   // n = zero row
        int s1 = (j1 < d) ? csr[beg + j1] : n;
        float2 v0 = x2[(size_t)s0 * 4 + c];
        float2 v1 = x2[(size_t)s1 * 4 + c];
        acc4(a, v0);
        acc4(a2, v1);
    }
#pragma unroll
    for (int k = 0; k < 4; k++) a[k] += a2[k];
#pragma unroll
    for (int k = 0; k < 4; k++) a[k] += __shfl_xor(a[k], 4, 64);
#pragma unroll
    for (int k = 0; k < 4; k++) a[k] += __shfl_xor(a[k], 8, 64);
    acc4(a, x2[(size_t)nodec * 4 + c]);   // self (replicated across g)
    float dvq = rsqrtf(1.0f + (float)d);
    if (g == 0) {
        int row = wave * 4 + q;
        half4v hv;
#pragma unroll
        for (int k = 0; k < 4; k++) hv[k] = (_Float16)(a[k] * dvq);
        *(half4v*)&xal[row][c * 4] = hv;
    }
    __syncthreads();
    // ---- GEMM1 (MFMA, K padded to 32): wave computes col-tiles 2w, 2w+1 ----
    int r = lane & 15, kg = lane >> 4;
    half8 axa = {0, 0, 0, 0, 0, 0, 0, 0};
    if (kg < 2) {
#pragma unroll
        for (int j = 0; j < 8; j++) axa[j] = xal[r][kg * 8 + j];
    }
#pragma unroll
    for (int ci = 0; ci < 2; ci++) {
        int ct = wave * 2 + ci;
        f32x4 acc = {0.f, 0.f, 0.f, 0.f};
        acc = __builtin_amdgcn_mfma_f32_16x16x32_f16(axa, w1f[ct * 64 + lane], acc, 0, 0, 0);
        float bb = b1[ct * 16 + r];
#pragma unroll
        for (int j = 0; j < 4; j++)
            h1l[kg * 4 + j][ct * 16 + r] = (_Float16)fmaxf(acc[j] + bb, 0.f);
    }
    __syncthreads();
    // ---- GEMM2 (MFMA): wave handles cols wave*32 .. +31 of t16 ----
    half8 af[4];
#pragma unroll
    for (int kc = 0; kc < 4; kc++)
        af[kc] = *(const half8*)&h1l[r][kc * 32 + kg * 8];
    float dv4[4];
#pragma unroll
    for (int j = 0; j < 4; j++) {
        int rowg = node0 + kg * 4 + j;
        dv4[j] = rsqrtf(1.0f + (float)deg[rowg < n ? rowg : n - 1]);
    }
#pragma unroll
    for (int ci = 0; ci < 2; ci++) {
        int ct = wave * 2 + ci;
        f32x4 acc = {0.f, 0.f, 0.f, 0.f};
#pragma unroll
        for (int kc = 0; kc < 4; kc++)
            acc = __builtin_amdgcn_mfma_f32_16x16x32_f16(af[kc], wf[(ct * 4 + kc) * 64 + lane], acc, 0, 0, 0);
#pragma unroll
        for (int j = 0; j < 4; j++) {
            int rowg = node0 + kg * 4 + j;
            if (rowg < n)
                t16[(size_t)rowg * HID + ct * 16 + r] = __float2half(acc[j] * dv4[j]);
        }
    }
}

// ================= 128-dim aggregate (fp16 in/out), branchless (R12 form) ====

__global__ __launch_bounds__(256) void k_agg128(const int* __restrict__ deg,
                                                const int* __restrict__ offs,
                                                const int* __restrict__ csr,
                                                const __half* __restrict__ t16,
                                                const float* __restrict__ b,
                                                __half* __restrict__ h2o, int n) {
    int wid = (blockIdx.x * blockDim.x + threadIdx.x) >> 6;
    int lane = threadIdx.x & 63;
    if (wid >= n) return;
    int q = lane >> 4, c = lane & 15;
    int d = deg[wid];
    int beg = offs[wid];
    const float4* t4 = (const float4*)t16;  // row = 16 float4 (256B)
    float a0[8] = {0,0,0,0,0,0,0,0};
    float a1[8] = {0,0,0,0,0,0,0,0};
    for (int j = 0; j < d; j += 16) {
        int j0 = j + q, j1 = j + 4 + q, j2 = j + 8 + q, j3 = j + 12 + q;
        int s0 = (j0 < d) ? csr[beg + j0] : n;   // n = zero row
        int s1 = (j1 < d) ? csr[beg + j1] : n;
        int s2 = (j2 < d) ? csr[beg + j2] : n;
        int s3 = (j3 < d) ? csr[beg + j3] : n;
        float4 v0 = t4[(size_t)s0 * 16 + c];
        float4 v1 = t4[(size_t)s1 * 16 + c];
        float4 v2 = t4[(size_t)s2 * 16 + c];
        float4 v3 = t4[(size_t)s3 * 16 + c];
        acc8(a0, v0);
        acc8(a1, v1);
        acc8(a0, v2);
        acc8(a1, v3);
    }
#pragma unroll
    for (int k = 0; k < 8; k++) a0[k] += a1[k];
#pragma unroll
    for (int k = 0; k < 8; k++) a0[k] += __shfl_xor(a0[k], 16, 64);
#pragma unroll
    for (int k = 0; k < 8; k++) a0[k] += __shfl_xor(a0[k], 32, 64);
    if (q == 0) {
        acc8(a0, t4[(size_t)wid * 16 + c]);   // self
        float dv = rsqrtf(1.0f + (float)d);
        float4 bb0 = ((const float4*)b)[c * 2];
        float4 bb1 = ((const float4*)b)[c * 2 + 1];
        float r[8];
        r[0] = fmaxf(fmaf(a0[0], dv, bb0.x), 0.f);
        r[1] = fmaxf(fmaf(a0[1], dv, bb0.y), 0.f);
        r[2] = fmaxf(fmaf(a0[2], dv, bb0.z), 0.f);
        r[3] = fmaxf(fmaf(a0[3], dv, bb0.w), 0.f);
        r[4] = fmaxf(fmaf(a0[4], dv, bb1.x), 0.f);
        r[5] = fmaxf(fmaf(a0[5], dv, bb1.y), 0.f);
        r[6] = fmaxf(fmaf(a0[6], dv, bb1.z), 0.f);
        r[7] = fmaxf(fmaf(a0[7], dv, bb1.w), 0.f);
        H4O u0, u1;
        u0.h2[0] = __floats2half2_rn(r[0], r[1]);
        u0.h2[1] = __floats2half2_rn(r[2], r[3]);
        u1.h2[0] = __floats2half2_rn(r[4], r[5]);
        u1.h2[1] = __floats2half2_rn(r[6], r[7]);
        float4 o = {u0.f2.x, u0.f2.y, u1.f2.x, u1.f2.y};
        ((float4*)h2o)[(size_t)wid * 16 + c] = o;
    }
}

// ================= GEMM3 on matrix cores: s16 = fp16((h2 @ W3pad16)*dis) =====

__global__ __launch_bounds__(256) void k_gemm3m(const __half* __restrict__ h2,
                                                const half8* __restrict__ wf3,
                                                const int* __restrict__ deg,
                                                __half* __restrict__ s16,
                                                int n, int ntiles) {
    int t = threadIdx.x;
    int wave = t >> 6, lane = t & 63;
    int tile = blockIdx.x * 4 + wave;
    if (tile >= ntiles) return;
    half8 B[4];
#pragma unroll
    for (int kc = 0; kc < 4; kc++) B[kc] = wf3[kc * 64 + lane];
    int r = lane & 15, kg = lane >> 4;
    const half8* h8 = (const half8*)h2;
    int row = tile * 16 + r;
    int rowc = row < n ? row : n - 1;
    half8 a[4];
#pragma unroll
    for (int kc = 0; kc < 4; kc++) a[kc] = h8[(size_t)rowc * 16 + kc * 4 + kg];
    f32x4 acc = {0.f, 0.f, 0.f, 0.f};
#pragma unroll
    for (int kc = 0; kc < 4; kc++)
        acc = __builtin_amdgcn_mfma_f32_16x16x32_f16(a[kc], B[kc], acc, 0, 0, 0);
#pragma unroll
    for (int j = 0; j < 4; j++) {
        int orow = tile * 16 + kg * 4 + j;
        if (orow < n) {
            float dv = rsqrtf(1.0f + (float)deg[orow]);
            s16[(size_t)orow * 16 + r] = __float2half(acc[j] * dv);
        }
    }
}

// ================= 15-dim aggregate, 4 nodes per wave =================

__global__ __launch_bounds__(256) void k_agg15(const int* __restrict__ deg,
                                               const int* __restrict__ offs,
                                               const int* __restrict__ csr,
                                               const __half* __restrict__ s16,
                                               const float* __restrict__ b,
                                               float* __restrict__ out, int n) {
    int wid = (blockIdx.x * blockDim.x + threadIdx.x) >> 6;
    int lane = threadIdx.x & 63;
    int q = lane >> 4, g = (lane >> 2) & 3, c = lane & 3;
    int node = wid * 4 + q;
    bool valid = node < n;
    int nodec = valid ? node : n - 1;
    int d = deg[nodec];
    int beg = offs[nodec];
    const float2* s2 = (const float2*)s16;  // row = 4 float2 (16 halfs padded)
    int dmax = d;
    dmax = max(dmax, __shfl_xor(dmax, 16, 64));
    dmax = max(dmax, __shfl_xor(dmax, 32, 64));
    float a[4]  = {0.f, 0.f, 0.f, 0.f};
    float b4[4] = {0.f, 0.f, 0.f, 0.f};
    for (int j = g; j < dmax; j += 8) {
        int j1 = j + 4;
        int s0 = (j  < d) ? csr[beg + j]  : n;   // n = zero row
        int s1 = (j1 < d) ? csr[beg + j1] : n;
        float2 v0 = s2[(size_t)s0 * 4 + c];
        float2 v1 = s2[(size_t)s1 * 4 + c];
        acc4(a, v0);
        acc4(b4, v1);
    }
#pragma unroll
    for (int k = 0; k < 4; k++) a[k] += b4[k];
#pragma unroll
    for (int k = 0; k < 4; k++) a[k] += __shfl_xor(a[k], 4, 64);
#pragma unroll
    for (int k = 0; k < 4; k++) a[k] += __shfl_xor(a[k], 8, 64);
    if (valid && g == 0) {
        acc4(a, s2[(size_t)node * 4 + c]);   // self
        float dv = rsqrtf(1.0f + (float)d);
#pragma unroll
        for (int k = 0; k < 4; k++) {
            int f = c * 4 + k;
            if (f < OUT_DIM)
                out[(size_t)node * OUT_DIM + f] = fmaf(a[k], dv, b[f]);
        }
    }
}

// ================= launch =================

extern "C" void kernel_launch(void* const* d_in, const int* in_sizes, int n_in,
                              void* d_out, int out_size, void* d_ws, size_t ws_size,
                              hipStream_t stream) {
    const float* x  = (const float*)d_in[0];
    const int*   ei = (const int*)d_in[1];
    const float* W1 = (const float*)d_in[2];
    const float* b1 = (const float*)d_in[3];
    const float* W2 = (const float*)d_in[4];
    const float* b2 = (const float*)d_in[5];
    const float* W3 = (const float*)d_in[6];
    const float* b3 = (const float*)d_in[7];
    int n = in_sizes[0] / IN_DIM;
    int e = in_sizes[1] / 2;
    const int* src = ei;
    const int* dst = ei + e;
    float* out = (float*)d_out;

    int nbkt = (n + BKT_SIZE - 1) / BKT_SIZE;   // 391

    // ---- workspace layout (256B-aligned segments) ----
    char* WS = (char*)d_ws;
    size_t off = 0;
    auto alloc = [&](size_t bytes) {
        char* p = WS + off;
        off = (off + bytes + 255) & ~(size_t)255;
        return p;
    };
    int*      deg  = (int*)     alloc((size_t)n * 4);
    int*      offs = (int*)     alloc((size_t)n * 4);
    int*      bcnt = (int*)     alloc((size_t)nbkt * CNT_STRIDE * 4);
    int*      ebuf = (int*)     alloc(((size_t)nbkt * BKT_CAP + 64) * 4);  // +pad for clamped over-reads
    __half*   xp   = (__half*)  alloc((size_t)(n + 1) * IN_DIM * 2);      // +1 zero row
    _Float16* wf   = (_Float16*)alloc((size_t)2048 * 8 * 2);
    _Float16* wf3  = (_Float16*)alloc((size_t)256 * 8 * 2);
    _Float16* w1f  = (_Float16*)alloc((size_t)512 * 8 * 2);
    __half*   t16  = (__half*)  alloc((size_t)(n + 1) * HID * 2);         // +1 zero row
    __half*   h2   = (__half*)  alloc((size_t)n * HID * 2);
    __half*   s16  = (__half*)  alloc((size_t)(n + 1) * 16 * 2);          // +1 zero row

    const int B = 256;
    int ntiles = (n + 15) / 16;   // 6250

    // ---- setup: W1/W2/W3 frags + bcnt zero + zero rows (one launch) ----
    k_setup<<<11, B, 0, stream>>>(W2, wf, W3, wf3, W1, w1f, bcnt, nbkt,
                                  xp + (size_t)n * IN_DIM,
                                  t16 + (size_t)n * HID,
                                  s16 + (size_t)n * 16);

    // ---- adjacency build (build also emits xp = fp16(dis*x)) ----
    k_bucket<<<(e + EPB - 1) / EPB, B, 0, stream>>>(src, dst, bcnt, ebuf, e, nbkt);
    k_build <<<nbkt, B, 0, stream>>>(bcnt, ebuf, deg, offs, x, xp, n);

    // ---- fused layer-1: agg16 + GEMM1 + GEMM2 (MFMA) -> t16 ----
    k_l1fused<<<ntiles, B, 0, stream>>>(deg, offs, ebuf, xp, (const half8*)w1f,
                                        b1, (const half8*)wf, t16, n);

    // ---- layer 2 aggregate -> h2 (fp16) ----
    k_agg128<<<((size_t)n * 64 + B - 1) / B, B, 0, stream>>>(deg, offs, ebuf, t16, b2, h2, n);

    // ---- layer 3: GEMM3 (MFMA) -> s16 ; agg15 (4 nodes/wave) -> out ----
    k_gemm3m<<<(ntiles + 3) / 4, B, 0, stream>>>(h2, (const half8*)wf3, deg, s16, n, ntiles);
    k_agg15 <<<((size_t)n * 16 + B - 1) / B, B, 0, stream>>>(deg, offs, ebuf, s16, b3, out, n);
}